// Round 13
// baseline (112.777 us; speedup 1.0000x reference)
//
#include <hip/hip_runtime.h>

#define NB 8192   // batch
#define NC 1024   // controller width (K)
#define NM 4096   // memory size (N)
#define NCH 16    // NM / 256 (256-col chunks per row)

typedef __attribute__((ext_vector_type(8))) short bf16x8;
typedef __attribute__((ext_vector_type(4))) float f32x4;

__device__ __forceinline__ unsigned short f2bf(float x) {
  unsigned int u = __float_as_uint(x);
  u += 0x7FFFu + ((u >> 16) & 1u);
  return (unsigned short)(u >> 16);
}
__device__ __forceinline__ float bf2f(unsigned short h) {
  return __uint_as_float(((unsigned int)h) << 16);
}
__device__ __forceinline__ unsigned int pk2(float a, float b) {
  return (unsigned int)f2bf(a) | ((unsigned int)f2bf(b) << 16);
}

__device__ __forceinline__ void gload_lds16(const void* g, void* l) {
  __builtin_amdgcn_global_load_lds(
      (const __attribute__((address_space(1))) unsigned int*)g,
      (__attribute__((address_space(3))) unsigned int*)l, 16, 0, 0);
}

#define DSR(dst, addr, IMM) \
  asm volatile("ds_read_b128 %0, %1 offset:" IMM : "=v"(dst) : "v"(addr))

// Raw barrier (no implicit waitcnt drain); "memory" orders compiler mem ops.
#define BAR asm volatile("s_barrier" ::: "memory")

// ------- Kernel 0: fused prep: W [K,N] f32 -> Wt [N,K] bf16  AND co -> bf16 ----
__global__ __launch_bounds__(256) void prep_k(const float* __restrict__ W,
                                              unsigned short* __restrict__ Wt,
                                              const float* __restrict__ coin,
                                              unsigned short* __restrict__ Abf) {
  __shared__ float tile[64][65];
  const int bid = blockIdx.x;
  const int t = threadIdx.x;
  if (bid < 1024) {  // ---- convW part ----
    const int n0 = (bid & 63) * 64, k0 = (bid >> 6) * 64;
    const int r = t >> 2, q = t & 3;
    const float4* src = reinterpret_cast<const float4*>(W + (size_t)(k0 + r) * NM + n0 + q * 16);
    float4 x0 = src[0], x1 = src[1], x2 = src[2], x3 = src[3];
    float* tr = &tile[r][q * 16];
    tr[0]=x0.x; tr[1]=x0.y; tr[2]=x0.z;  tr[3]=x0.w;
    tr[4]=x1.x; tr[5]=x1.y; tr[6]=x1.z;  tr[7]=x1.w;
    tr[8]=x2.x; tr[9]=x2.y; tr[10]=x2.z; tr[11]=x2.w;
    tr[12]=x3.x; tr[13]=x3.y; tr[14]=x3.z; tr[15]=x3.w;
    __syncthreads();
    unsigned int pk[8];
#pragma unroll
    for (int i = 0; i < 8; ++i)
      pk[i] = pk2(tile[q * 16 + 2 * i][r], tile[q * 16 + 2 * i + 1][r]);
    int4* dst = reinterpret_cast<int4*>(Wt + (size_t)(n0 + r) * NC + k0 + q * 16);
    dst[0] = make_int4((int)pk[0], (int)pk[1], (int)pk[2], (int)pk[3]);
    dst[1] = make_int4((int)pk[4], (int)pk[5], (int)pk[6], (int)pk[7]);
  } else {  // ---- convA part ----
    const size_t i = ((size_t)(bid - 1024) * 256 + t) * 8;
    const float4* s = reinterpret_cast<const float4*>(coin + i);
    float4 x0 = s[0], x1 = s[1];
    int4 o = make_int4((int)pk2(x0.x, x0.y), (int)pk2(x0.z, x0.w),
                       (int)pk2(x1.x, x1.y), (int)pk2(x1.z, x1.w));
    *reinterpret_cast<int4*>(Abf + i) = o;
  }
}

// ------- Kernel 2: 256x256-tile 8-phase bf16 MFMA GEMM, fragment register
//         double-buffering, raw barriers, T1 chunked XCD swizzle
//         + two-phase fused epilogue -------
__global__ __launch_bounds__(512) void gemm_fused(
    const unsigned short* __restrict__ Abf, const float* __restrict__ memry,
    const unsigned short* __restrict__ Wt, const float* __restrict__ bvec,
    float* __restrict__ pdotg, float* __restrict__ pesqg,
    float* __restrict__ pmsqg, float* __restrict__ pmsg) {
  __shared__ __align__(16) unsigned short LDS[2][4][8192];  // 128 KiB
  // T1 chunked XCD swizzle: dispatch s lands on XCD s%8; give XCD x the
  // contiguous block range [64x, 64x+64) of bn-major order -> its 32
  // concurrent CUs share ONE 512 KB B-panel (L2-resident).
  const int s = blockIdx.y * 32 + blockIdx.x;   // dispatch order (x fastest)
  const int orig = (s & 7) * 64 + (s >> 3);     // bijective (512 % 8 == 0)
  const int bn = orig >> 5, bm = orig & 31;     // bn-major linearization
  const int row0 = bm * 256, col0 = bn * 256;
  const int t = threadIdx.x;
  const int wid = t >> 6, lane = t & 63;
  const int wr = wid >> 2, wc = wid & 3;          // 2 x 4 waves
  const int l15 = lane & 15, lg = lane >> 4;
  const int ga8 = (lg ^ ((l15 >> 1) & 3)) * 8;    // swizzled k-granule (halfwords)

  f32x4 acc[8][4];
#pragma unroll
  for (int mi = 0; mi < 8; ++mi)
#pragma unroll
    for (int ni = 0; ni < 4; ++ni) acc[mi][ni] = (f32x4){0.f, 0.f, 0.f, 0.f};

  const unsigned ldsbase =
      (unsigned)(uintptr_t)(__attribute__((address_space(3))) void*)&LDS[0][0][0];
  const unsigned abase = ldsbase + ((wr * 128 + l15) * 32 + ga8) * 2;
  const unsigned bbase = ldsbase + 32768 + ((wc * 64 + l15) * 32 + ga8) * 2;

  const int srow0 = t >> 2;
  const int sk8 = ((t & 3) ^ ((srow0 >> 1) & 3)) * 8;
  const unsigned short* gA = Abf + (size_t)(row0 + srow0) * NC + sk8;
  const unsigned short* gB = Wt + (size_t)(col0 + srow0) * NC + sk8;

#define STG(SL, TY, KT)                                                      \
  {                                                                          \
    const unsigned short* s0 = ((TY) <= 1 ? gA : gB) + (KT) * 64 + ((TY)&1) * 32; \
    gload_lds16(s0, &LDS[SL][TY][t * 8]);                                    \
    gload_lds16(s0 + (size_t)128 * NC, &LDS[SL][TY][t * 8 + 4096]);          \
  }
#define NOSTG
#define VM10 asm volatile("s_waitcnt vmcnt(10)" ::: "memory")
#define VM8 asm volatile("s_waitcnt vmcnt(8)" ::: "memory")
#define VM4 asm volatile("s_waitcnt vmcnt(4)" ::: "memory")
#define VM0 asm volatile("s_waitcnt vmcnt(0)" ::: "memory")
#define NOVM

  // phase p: [ds_reads for p+1] [stage] [vm] [BAR] [lgkmcnt(N)]
  //          [MFMA on regs read at p-1] [BAR]
#define PH(ACCH, AMF, BMF, LDB, BLD, LDA, ALD, NSL, NS, NMH, STAGE, VM, LGK) \
  {                                                                          \
    if (LDB) {                                                               \
      const unsigned ba = bbase + (NSL)*65536 + (NS)*16384;                  \
      DSR(BLD[0], ba, "0");    DSR(BLD[1], ba, "1024");                      \
      DSR(BLD[2], ba, "2048"); DSR(BLD[3], ba, "3072");                      \
    }                                                                        \
    if (LDA) {                                                               \
      const unsigned aa = abase + (NSL)*65536 + (NS)*16384 + (NMH)*4096;     \
      DSR(ALD[0], aa, "0");    DSR(ALD[1], aa, "1024");                      \
      DSR(ALD[2], aa, "2048"); DSR(ALD[3], aa, "3072");                      \
    }                                                                        \
    STAGE;                                                                   \
    VM;                                                                      \
    BAR;                                                                     \
    asm volatile("s_waitcnt lgkmcnt(" LGK ")" ::: "memory");                 \
    __builtin_amdgcn_sched_barrier(0);                                       \
    __builtin_amdgcn_s_setprio(1);                                           \
    _Pragma("unroll") for (int mi = 0; mi < 4; ++mi)                         \
        _Pragma("unroll") for (int ni = 0; ni < 4; ++ni)                     \
            acc[(ACCH)*4 + mi][ni] = __builtin_amdgcn_mfma_f32_16x16x32_bf16(\
                AMF[mi], BMF[ni], acc[(ACCH)*4 + mi][ni], 0, 0, 0);          \
    __builtin_amdgcn_s_setprio(0);                                           \
    BAR;                                                                     \
    __builtin_amdgcn_sched_barrier(0);                                       \
  }

  // ---- prologue: slot0 (K-tile 0) + slot1 minus Ak1 (K-tile 1) ----
  STG(0, 2, 0); STG(0, 0, 0); STG(0, 3, 0); STG(0, 1, 0);
  STG(1, 2, 1); STG(1, 0, 1); STG(1, 3, 1);
  VM10;  // retire first 2 STGs (slot0 B-k0, A-k0)
  BAR;
  __builtin_amdgcn_sched_barrier(0);

  bf16x8 aA[4], aB[4], bA[4], bB[4];
  // fragments for t1: B from LDS[0][2], A from LDS[0][0] MH0
  {
    const unsigned ba = bbase;
    DSR(bA[0], ba, "0");    DSR(bA[1], ba, "1024");
    DSR(bA[2], ba, "2048"); DSR(bA[3], ba, "3072");
    const unsigned aa = abase;
    DSR(aA[0], aa, "0");    DSR(aA[1], aa, "1024");
    DSR(aA[2], aa, "2048"); DSR(aA[3], aa, "3072");
  }

  // ---- main loop: 7 iterations x 2 K-tiles ----
  for (int it = 0; it < 7; ++it) {
    const int c1 = 2 * it + 1, c2 = 2 * it + 2, c3 = 2 * it + 3;
    PH(0, aA, bA, 0, bB, 1, aB, 0, 0, 1, STG(1, 1, c1), VM8,  "4");  // t1
    PH(1, aB, bA, 1, bB, 1, aA, 0, 1, 0, STG(0, 2, c2), NOVM, "8");  // t2
    PH(0, aA, bB, 0, bA, 1, aB, 0, 1, 1, STG(0, 0, c2), VM8,  "4");  // t3
    PH(1, aB, bB, 1, bA, 1, aA, 1, 0, 0, STG(0, 3, c2), NOVM, "8");  // t4
    PH(0, aA, bA, 0, bB, 1, aB, 1, 0, 1, STG(0, 1, c2), VM8,  "4");  // t5
    PH(1, aB, bA, 1, bB, 1, aA, 1, 1, 0, STG(1, 2, c3), NOVM, "8");  // t6
    PH(0, aA, bB, 0, bA, 1, aB, 1, 1, 1, STG(1, 0, c3), VM8,  "4");  // t7
    PH(1, aB, bB, 1, bA, 1, aA, 0, 0, 0, STG(1, 3, c3), NOVM, "8");  // t8
  }
  // ---- final iteration (K-tiles 14, 15): drain vmcnt VM8 -> VM4 -> VM0 ----
  PH(0, aA, bA, 0, bB, 1, aB, 0, 0, 1, STG(1, 1, 15), VM8,  "4");  // f1
  PH(1, aB, bA, 1, bB, 1, aA, 0, 1, 0, NOSTG,         NOVM, "8");  // f2
  PH(0, aA, bB, 0, bA, 1, aB, 0, 1, 1, NOSTG,         VM4,  "4");  // f3
  PH(1, aB, bB, 1, bA, 1, aA, 1, 0, 0, NOSTG,         NOVM, "8");  // f4
  PH(0, aA, bA, 0, bB, 1, aB, 1, 0, 1, NOSTG,         VM0,  "4");  // f5
  PH(1, aB, bA, 1, bB, 1, aA, 1, 1, 0, NOSTG,         NOVM, "8");  // f6
  PH(0, aA, bB, 0, bA, 1, aB, 1, 1, 1, NOSTG,         NOVM, "4");  // f7
  PH(1, aB, bB, 0, bA, 0, aA, 0, 0, 0, NOSTG,         NOVM, "0");  // f8
#undef PH
#undef STG

  // ---- E1: e = exp(z + b) -> bf16 into LDS [256][256], col-XOR banks ----
  unsigned short (*e_lds)[256] = reinterpret_cast<unsigned short(*)[256]>(&LDS[0][0][0]);
  float bv[4];
#pragma unroll
  for (int ni = 0; ni < 4; ++ni) bv[ni] = bvec[col0 + wc * 64 + ni * 16 + l15];
#pragma unroll
  for (int mi = 0; mi < 8; ++mi)
#pragma unroll
    for (int ni = 0; ni < 4; ++ni)
#pragma unroll
      for (int j = 0; j < 4; ++j) {
        const int rl = wr * 128 + mi * 16 + 4 * lg + j;
        const int cl = wc * 64 + ni * 16 + l15;
        e_lds[rl][cl ^ (((rl >> 2) & 3) << 4)] = f2bf(__expf(acc[mi][ni][j] + bv[ni]));
      }
  __syncthreads();

  // ---- E2: coalesced fused pass: per row, partials of e*m, e^2, m^2, m ----
  {
    const int halfl = lane >> 5, l31 = lane & 31;
    const int rbase = wid * 32;  // each wave owns 32 consecutive rows
#pragma unroll 8
    for (int i = 0; i < 16; ++i) {
      const int rl = rbase + 2 * i + halfl;
      const float4* mp = reinterpret_cast<const float4*>(
          memry + (size_t)(row0 + rl) * NM + col0 + l31 * 8);
      float4 m0 = mp[0], m1 = mp[1];
      bf16x8 ev = *reinterpret_cast<const bf16x8*>(
          &e_lds[rl][(l31 * 8) ^ (((rl >> 2) & 3) << 4)]);
      float mv[8] = {m0.x, m0.y, m0.z, m0.w, m1.x, m1.y, m1.z, m1.w};
      float pd = 0.f, pe = 0.f, pq = 0.f, pm = 0.f;
#pragma unroll
      for (int k = 0; k < 8; ++k) {
        float e = bf2f((unsigned short)ev[k]);
        pd += e * mv[k]; pe += e * e; pq += mv[k] * mv[k]; pm += mv[k];
      }
#pragma unroll
      for (int sh = 1; sh < 32; sh <<= 1) {
        pd += __shfl_xor(pd, sh); pe += __shfl_xor(pe, sh);
        pq += __shfl_xor(pq, sh); pm += __shfl_xor(pm, sh);
      }
      if (l31 == 0) {
        const int idx = (row0 + rl) * NCH + bn;
        pdotg[idx] = pd; pesqg[idx] = pe; pmsqg[idx] = pq; pmsg[idx] = pm;
      }
    }
  }
}

// ---------------- Kernel 3: reduce partials -> sims, msum ----------------
__global__ __launch_bounds__(256) void finalize_k(
    const float* __restrict__ pd, const float* __restrict__ pe,
    const float* __restrict__ pq, const float* __restrict__ pm,
    float* __restrict__ sims, float* __restrict__ mst) {
  const int r = blockIdx.x * 256 + threadIdx.x;
  float d = 0.f, e = 0.f, q = 0.f, m = 0.f;
#pragma unroll
  for (int i = 0; i < NCH; ++i) {
    d += pd[r * NCH + i];
    e += pe[r * NCH + i];
    q += pq[r * NCH + i];
    m += pm[r * NCH + i];
  }
  sims[r] = -d / (sqrtf(fmaxf(e, 1e-12f)) * sqrtf(fmaxf(q, 1e-12f)));
  mst[r] = m;
}

// ------------- Kernel 4: softmax over B=8192 + final scaling -------------
__global__ __launch_bounds__(1024) void softmax_out_k(
    const float* __restrict__ sims, const float* __restrict__ mst,
    float* __restrict__ out) {
  __shared__ float red[16];
  const int t = threadIdx.x;
  float v[8];
  float mx = -1e30f;
#pragma unroll
  for (int i = 0; i < 8; ++i) {
    v[i] = sims[t + i * 1024];
    mx = fmaxf(mx, v[i]);
  }
#pragma unroll
  for (int s = 1; s < 64; s <<= 1) mx = fmaxf(mx, __shfl_xor(mx, s));
  if ((t & 63) == 0) red[t >> 6] = mx;
  __syncthreads();
  float m2 = red[0];
#pragma unroll
  for (int i = 1; i < 16; ++i) m2 = fmaxf(m2, red[i]);
  mx = m2;
  float sum = 0.f;
#pragma unroll
  for (int i = 0; i < 8; ++i) sum += __expf(v[i] - mx);
#pragma unroll
  for (int s = 1; s < 64; s <<= 1) sum += __shfl_xor(sum, s);
  __syncthreads();
  if ((t & 63) == 0) red[t >> 6] = sum;
  __syncthreads();
  float s2 = 0.f;
#pragma unroll
  for (int i = 0; i < 16; ++i) s2 += red[i];
  const float inv = 1.0f / s2;
#pragma unroll
  for (int i = 0; i < 8; ++i)
    out[t + i * 1024] = __expf(v[i] - mx) * inv * mst[t + i * 1024];
}

extern "C" void kernel_launch(void* const* d_in, const int* in_sizes, int n_in,
                              void* d_out, int out_size, void* d_ws, size_t ws_size,
                              hipStream_t stream) {
  const float* memry = (const float*)d_in[0];  // [B, M]
  const float* co    = (const float*)d_in[1];  // [B, C]
  const float* W     = (const float*)d_in[2];  // [C, M]
  const float* bvec  = (const float*)d_in[3];  // [M]
  float* out = (float*)d_out;                  // [B]

  char* w = (char*)d_ws;
  unsigned short* Wt  = (unsigned short*)w;                       // 8 MiB
  unsigned short* Abf = Wt + (size_t)NM * NC;                     // 16 MiB
  float* pdot = (float*)(Abf + (size_t)NB * NC);                  // 8192*16 f32 each
  float* pesq = pdot + (size_t)NB * NCH;
  float* pmsq = pesq + (size_t)NB * NCH;
  float* pms  = pmsq + (size_t)NB * NCH;
  float* sims = pms  + (size_t)NB * NCH;
  float* mst  = sims + NB;

  prep_k<<<1024 + (size_t)NB * NC / (256 * 8), 256, 0, stream>>>(W, Wt, co, Abf);
  gemm_fused<<<dim3(32, 16), 512, 0, stream>>>(Abf, memry, Wt, bvec,
                                               pdot, pesq, pmsq, pms);
  finalize_k<<<NB / 256, 256, 0, stream>>>(pdot, pesq, pmsq, pms, sims, mst);
  softmax_out_k<<<1, 1024, 0, stream>>>(sims, mst, out);
}

// Round 14
// 106.061 us; speedup vs baseline: 1.0633x; 1.0633x over previous
//
#include <hip/hip_runtime.h>

#define NB 8192   // batch
#define NC 1024   // controller width (K)
#define NM 4096   // memory size (N)
#define NCH 16    // NM / 256 (256-col chunks per row)

typedef __attribute__((ext_vector_type(8))) short bf16x8;
typedef __attribute__((ext_vector_type(4))) float f32x4;

__device__ __forceinline__ unsigned short f2bf(float x) {
  unsigned int u = __float_as_uint(x);
  u += 0x7FFFu + ((u >> 16) & 1u);
  return (unsigned short)(u >> 16);
}
__device__ __forceinline__ float bf2f(unsigned short h) {
  return __uint_as_float(((unsigned int)h) << 16);
}
__device__ __forceinline__ unsigned int pk2(float a, float b) {
  return (unsigned int)f2bf(a) | ((unsigned int)f2bf(b) << 16);
}

__device__ __forceinline__ void gload_lds16(const void* g, void* l) {
  __builtin_amdgcn_global_load_lds(
      (const __attribute__((address_space(1))) unsigned int*)g,
      (__attribute__((address_space(3))) unsigned int*)l, 16, 0, 0);
}

#define DSR(dst, addr, IMM) \
  asm volatile("ds_read_b128 %0, %1 offset:" IMM : "=v"(dst) : "v"(addr))

// Raw barrier (no implicit waitcnt drain); "memory" orders compiler mem ops.
#define BAR asm volatile("s_barrier" ::: "memory")

// ------- Kernel 0: fused prep: W [K,N] f32 -> Wt [N,K] bf16  AND co -> bf16 ----
__global__ __launch_bounds__(256) void prep_k(const float* __restrict__ W,
                                              unsigned short* __restrict__ Wt,
                                              const float* __restrict__ coin,
                                              unsigned short* __restrict__ Abf) {
  __shared__ float tile[64][65];
  const int bid = blockIdx.x;
  const int t = threadIdx.x;
  if (bid < 1024) {  // ---- convW part ----
    const int n0 = (bid & 63) * 64, k0 = (bid >> 6) * 64;
    const int r = t >> 2, q = t & 3;
    const float4* src = reinterpret_cast<const float4*>(W + (size_t)(k0 + r) * NM + n0 + q * 16);
    float4 x0 = src[0], x1 = src[1], x2 = src[2], x3 = src[3];
    float* tr = &tile[r][q * 16];
    tr[0]=x0.x; tr[1]=x0.y; tr[2]=x0.z;  tr[3]=x0.w;
    tr[4]=x1.x; tr[5]=x1.y; tr[6]=x1.z;  tr[7]=x1.w;
    tr[8]=x2.x; tr[9]=x2.y; tr[10]=x2.z; tr[11]=x2.w;
    tr[12]=x3.x; tr[13]=x3.y; tr[14]=x3.z; tr[15]=x3.w;
    __syncthreads();
    unsigned int pk[8];
#pragma unroll
    for (int i = 0; i < 8; ++i)
      pk[i] = pk2(tile[q * 16 + 2 * i][r], tile[q * 16 + 2 * i + 1][r]);
    int4* dst = reinterpret_cast<int4*>(Wt + (size_t)(n0 + r) * NC + k0 + q * 16);
    dst[0] = make_int4((int)pk[0], (int)pk[1], (int)pk[2], (int)pk[3]);
    dst[1] = make_int4((int)pk[4], (int)pk[5], (int)pk[6], (int)pk[7]);
  } else {  // ---- convA part ----
    const size_t i = ((size_t)(bid - 1024) * 256 + t) * 8;
    const float4* s = reinterpret_cast<const float4*>(coin + i);
    float4 x0 = s[0], x1 = s[1];
    int4 o = make_int4((int)pk2(x0.x, x0.y), (int)pk2(x0.z, x0.w),
                       (int)pk2(x1.x, x1.y), (int)pk2(x1.z, x1.w));
    *reinterpret_cast<int4*>(Abf + i) = o;
  }
}

// ------- Kernel 2: 256x256-tile 8-phase bf16 MFMA GEMM, fragment register
//         double-buffering, SINGLE raw barrier per phase
//         + two-phase fused epilogue -------
// Hazard ledger (1 bar/phase): per-wave order reads->lgkm->MFMA unchanged;
// WAR: STG(q) vs reads(p<q): reads complete at lgkm(p) before BAR(p) < STG(q);
// RAW: VM(q) before BAR(q) < reads(q+1); same-phase STG/read targets disjoint.
__global__ __launch_bounds__(512) void gemm_fused(
    const unsigned short* __restrict__ Abf, const float* __restrict__ memry,
    const unsigned short* __restrict__ Wt, const float* __restrict__ bvec,
    float* __restrict__ pdotg, float* __restrict__ pesqg,
    float* __restrict__ pmsqg, float* __restrict__ pmsg) {
  __shared__ __align__(16) unsigned short LDS[2][4][8192];  // 128 KiB
  const int bm = blockIdx.x, bn = blockIdx.y;
  const int row0 = bm * 256, col0 = bn * 256;
  const int t = threadIdx.x;
  const int wid = t >> 6, lane = t & 63;
  const int wr = wid >> 2, wc = wid & 3;          // 2 x 4 waves
  const int l15 = lane & 15, lg = lane >> 4;
  const int ga8 = (lg ^ ((l15 >> 1) & 3)) * 8;    // swizzled k-granule (halfwords)

  f32x4 acc[8][4];
#pragma unroll
  for (int mi = 0; mi < 8; ++mi)
#pragma unroll
    for (int ni = 0; ni < 4; ++ni) acc[mi][ni] = (f32x4){0.f, 0.f, 0.f, 0.f};

  const unsigned ldsbase =
      (unsigned)(uintptr_t)(__attribute__((address_space(3))) void*)&LDS[0][0][0];
  const unsigned abase = ldsbase + ((wr * 128 + l15) * 32 + ga8) * 2;
  const unsigned bbase = ldsbase + 32768 + ((wc * 64 + l15) * 32 + ga8) * 2;

  const int srow0 = t >> 2;
  const int sk8 = ((t & 3) ^ ((srow0 >> 1) & 3)) * 8;
  const unsigned short* gA = Abf + (size_t)(row0 + srow0) * NC + sk8;
  const unsigned short* gB = Wt + (size_t)(col0 + srow0) * NC + sk8;

#define STG(SL, TY, KT)                                                      \
  {                                                                          \
    const unsigned short* s0 = ((TY) <= 1 ? gA : gB) + (KT) * 64 + ((TY)&1) * 32; \
    gload_lds16(s0, &LDS[SL][TY][t * 8]);                                    \
    gload_lds16(s0 + (size_t)128 * NC, &LDS[SL][TY][t * 8 + 4096]);          \
  }
#define NOSTG
#define VM10 asm volatile("s_waitcnt vmcnt(10)" ::: "memory")
#define VM8 asm volatile("s_waitcnt vmcnt(8)" ::: "memory")
#define VM4 asm volatile("s_waitcnt vmcnt(4)" ::: "memory")
#define VM0 asm volatile("s_waitcnt vmcnt(0)" ::: "memory")
#define NOVM

  // phase p: [ds_reads for p+1] [stage] [vm] [lgkmcnt(N)]
  //          [MFMA on regs read at p-1] [BAR]
#define PH(ACCH, AMF, BMF, LDB, BLD, LDA, ALD, NSL, NS, NMH, STAGE, VM, LGK) \
  {                                                                          \
    if (LDB) {                                                               \
      const unsigned ba = bbase + (NSL)*65536 + (NS)*16384;                  \
      DSR(BLD[0], ba, "0");    DSR(BLD[1], ba, "1024");                      \
      DSR(BLD[2], ba, "2048"); DSR(BLD[3], ba, "3072");                      \
    }                                                                        \
    if (LDA) {                                                               \
      const unsigned aa = abase + (NSL)*65536 + (NS)*16384 + (NMH)*4096;     \
      DSR(ALD[0], aa, "0");    DSR(ALD[1], aa, "1024");                      \
      DSR(ALD[2], aa, "2048"); DSR(ALD[3], aa, "3072");                      \
    }                                                                        \
    STAGE;                                                                   \
    VM;                                                                      \
    asm volatile("s_waitcnt lgkmcnt(" LGK ")" ::: "memory");                 \
    __builtin_amdgcn_sched_barrier(0);                                       \
    __builtin_amdgcn_s_setprio(1);                                           \
    _Pragma("unroll") for (int mi = 0; mi < 4; ++mi)                         \
        _Pragma("unroll") for (int ni = 0; ni < 4; ++ni)                     \
            acc[(ACCH)*4 + mi][ni] = __builtin_amdgcn_mfma_f32_16x16x32_bf16(\
                AMF[mi], BMF[ni], acc[(ACCH)*4 + mi][ni], 0, 0, 0);          \
    __builtin_amdgcn_s_setprio(0);                                           \
    BAR;                                                                     \
    __builtin_amdgcn_sched_barrier(0);                                       \
  }

  // ---- prologue: slot0 (K-tile 0) + slot1 minus Ak1 (K-tile 1) ----
  STG(0, 2, 0); STG(0, 0, 0); STG(0, 3, 0); STG(0, 1, 0);
  STG(1, 2, 1); STG(1, 0, 1); STG(1, 3, 1);
  VM10;  // retire first 2 STGs (slot0 B-k0, A-k0)
  BAR;
  __builtin_amdgcn_sched_barrier(0);

  bf16x8 aA[4], aB[4], bA[4], bB[4];
  // fragments for t1: B from LDS[0][2], A from LDS[0][0] MH0
  {
    const unsigned ba = bbase;
    DSR(bA[0], ba, "0");    DSR(bA[1], ba, "1024");
    DSR(bA[2], ba, "2048"); DSR(bA[3], ba, "3072");
    const unsigned aa = abase;
    DSR(aA[0], aa, "0");    DSR(aA[1], aa, "1024");
    DSR(aA[2], aa, "2048"); DSR(aA[3], aa, "3072");
  }

  // ---- main loop: 7 iterations x 2 K-tiles ----
  for (int it = 0; it < 7; ++it) {
    const int c1 = 2 * it + 1, c2 = 2 * it + 2, c3 = 2 * it + 3;
    PH(0, aA, bA, 0, bB, 1, aB, 0, 0, 1, STG(1, 1, c1), VM8,  "4");  // t1
    PH(1, aB, bA, 1, bB, 1, aA, 0, 1, 0, STG(0, 2, c2), NOVM, "8");  // t2
    PH(0, aA, bB, 0, bA, 1, aB, 0, 1, 1, STG(0, 0, c2), VM8,  "4");  // t3
    PH(1, aB, bB, 1, bA, 1, aA, 1, 0, 0, STG(0, 3, c2), NOVM, "8");  // t4
    PH(0, aA, bA, 0, bB, 1, aB, 1, 0, 1, STG(0, 1, c2), VM8,  "4");  // t5
    PH(1, aB, bA, 1, bB, 1, aA, 1, 1, 0, STG(1, 2, c3), NOVM, "8");  // t6
    PH(0, aA, bB, 0, bA, 1, aB, 1, 1, 1, STG(1, 0, c3), VM8,  "4");  // t7
    PH(1, aB, bB, 1, bA, 1, aA, 0, 0, 0, STG(1, 3, c3), NOVM, "8");  // t8
  }
  // ---- final iteration (K-tiles 14, 15): drain vmcnt VM8 -> VM4 -> VM0 ----
  PH(0, aA, bA, 0, bB, 1, aB, 0, 0, 1, STG(1, 1, 15), VM8,  "4");  // f1
  PH(1, aB, bA, 1, bB, 1, aA, 0, 1, 0, NOSTG,         NOVM, "8");  // f2
  PH(0, aA, bB, 0, bA, 1, aB, 0, 1, 1, NOSTG,         VM4,  "4");  // f3
  PH(1, aB, bB, 1, bA, 1, aA, 1, 0, 0, NOSTG,         NOVM, "8");  // f4
  PH(0, aA, bA, 0, bB, 1, aB, 1, 0, 1, NOSTG,         VM0,  "4");  // f5
  PH(1, aB, bA, 1, bB, 1, aA, 1, 1, 0, NOSTG,         NOVM, "8");  // f6
  PH(0, aA, bB, 0, bA, 1, aB, 1, 1, 1, NOSTG,         NOVM, "4");  // f7
  PH(1, aB, bB, 0, bA, 0, aA, 0, 0, 0, NOSTG,         NOVM, "0");  // f8
#undef PH
#undef STG

  // ---- E1: e = exp(z + b) -> bf16 into LDS [256][256], col-XOR banks ----
  unsigned short (*e_lds)[256] = reinterpret_cast<unsigned short(*)[256]>(&LDS[0][0][0]);
  float bv[4];
#pragma unroll
  for (int ni = 0; ni < 4; ++ni) bv[ni] = bvec[col0 + wc * 64 + ni * 16 + l15];
#pragma unroll
  for (int mi = 0; mi < 8; ++mi)
#pragma unroll
    for (int ni = 0; ni < 4; ++ni)
#pragma unroll
      for (int j = 0; j < 4; ++j) {
        const int rl = wr * 128 + mi * 16 + 4 * lg + j;
        const int cl = wc * 64 + ni * 16 + l15;
        e_lds[rl][cl ^ (((rl >> 2) & 3) << 4)] = f2bf(__expf(acc[mi][ni][j] + bv[ni]));
      }
  __syncthreads();

  // ---- E2: coalesced fused pass: per row, partials of e*m, e^2, m^2, m ----
  {
    const int halfl = lane >> 5, l31 = lane & 31;
    const int rbase = wid * 32;  // each wave owns 32 consecutive rows
#pragma unroll 8
    for (int i = 0; i < 16; ++i) {
      const int rl = rbase + 2 * i + halfl;
      const float4* mp = reinterpret_cast<const float4*>(
          memry + (size_t)(row0 + rl) * NM + col0 + l31 * 8);
      float4 m0 = mp[0], m1 = mp[1];
      bf16x8 ev = *reinterpret_cast<const bf16x8*>(
          &e_lds[rl][(l31 * 8) ^ (((rl >> 2) & 3) << 4)]);
      float mv[8] = {m0.x, m0.y, m0.z, m0.w, m1.x, m1.y, m1.z, m1.w};
      float pd = 0.f, pe = 0.f, pq = 0.f, pm = 0.f;
#pragma unroll
      for (int k = 0; k < 8; ++k) {
        float e = bf2f((unsigned short)ev[k]);
        pd += e * mv[k]; pe += e * e; pq += mv[k] * mv[k]; pm += mv[k];
      }
#pragma unroll
      for (int sh = 1; sh < 32; sh <<= 1) {
        pd += __shfl_xor(pd, sh); pe += __shfl_xor(pe, sh);
        pq += __shfl_xor(pq, sh); pm += __shfl_xor(pm, sh);
      }
      if (l31 == 0) {
        const int idx = (row0 + rl) * NCH + bn;
        pdotg[idx] = pd; pesqg[idx] = pe; pmsqg[idx] = pq; pmsg[idx] = pm;
      }
    }
  }
}

// ---------------- Kernel 3: reduce partials -> sims, msum ----------------
__global__ __launch_bounds__(256) void finalize_k(
    const float* __restrict__ pd, const float* __restrict__ pe,
    const float* __restrict__ pq, const float* __restrict__ pm,
    float* __restrict__ sims, float* __restrict__ mst) {
  const int r = blockIdx.x * 256 + threadIdx.x;
  float d = 0.f, e = 0.f, q = 0.f, m = 0.f;
#pragma unroll
  for (int i = 0; i < NCH; ++i) {
    d += pd[r * NCH + i];
    e += pe[r * NCH + i];
    q += pq[r * NCH + i];
    m += pm[r * NCH + i];
  }
  sims[r] = -d / (sqrtf(fmaxf(e, 1e-12f)) * sqrtf(fmaxf(q, 1e-12f)));
  mst[r] = m;
}

// ------------- Kernel 4: softmax over B=8192 + final scaling -------------
__global__ __launch_bounds__(1024) void softmax_out_k(
    const float* __restrict__ sims, const float* __restrict__ mst,
    float* __restrict__ out) {
  __shared__ float red[16];
  const int t = threadIdx.x;
  float v[8];
  float mx = -1e30f;
#pragma unroll
  for (int i = 0; i < 8; ++i) {
    v[i] = sims[t + i * 1024];
    mx = fmaxf(mx, v[i]);
  }
#pragma unroll
  for (int s = 1; s < 64; s <<= 1) mx = fmaxf(mx, __shfl_xor(mx, s));
  if ((t & 63) == 0) red[t >> 6] = mx;
  __syncthreads();
  float m2 = red[0];
#pragma unroll
  for (int i = 1; i < 16; ++i) m2 = fmaxf(m2, red[i]);
  mx = m2;
  float sum = 0.f;
#pragma unroll
  for (int i = 0; i < 8; ++i) sum += __expf(v[i] - mx);
#pragma unroll
  for (int s = 1; s < 64; s <<= 1) sum += __shfl_xor(sum, s);
  __syncthreads();
  if ((t & 63) == 0) red[t >> 6] = sum;
  __syncthreads();
  float s2 = 0.f;
#pragma unroll
  for (int i = 0; i < 16; ++i) s2 += red[i];
  const float inv = 1.0f / s2;
#pragma unroll
  for (int i = 0; i < 8; ++i)
    out[t + i * 1024] = __expf(v[i] - mx) * inv * mst[t + i * 1024];
}

extern "C" void kernel_launch(void* const* d_in, const int* in_sizes, int n_in,
                              void* d_out, int out_size, void* d_ws, size_t ws_size,
                              hipStream_t stream) {
  const float* memry = (const float*)d_in[0];  // [B, M]
  const float* co    = (const float*)d_in[1];  // [B, C]
  const float* W     = (const float*)d_in[2];  // [C, M]
  const float* bvec  = (const float*)d_in[3];  // [M]
  float* out = (float*)d_out;                  // [B]

  char* w = (char*)d_ws;
  unsigned short* Wt  = (unsigned short*)w;                       // 8 MiB
  unsigned short* Abf = Wt + (size_t)NM * NC;                     // 16 MiB
  float* pdot = (float*)(Abf + (size_t)NB * NC);                  // 8192*16 f32 each
  float* pesq = pdot + (size_t)NB * NCH;
  float* pmsq = pesq + (size_t)NB * NCH;
  float* pms  = pmsq + (size_t)NB * NCH;
  float* sims = pms  + (size_t)NB * NCH;
  float* mst  = sims + NB;

  prep_k<<<1024 + (size_t)NB * NC / (256 * 8), 256, 0, stream>>>(W, Wt, co, Abf);
  gemm_fused<<<dim3(NB / 256, NM / 256), 512, 0, stream>>>(Abf, memry, Wt, bvec,
                                                           pdot, pesq, pmsq, pms);
  finalize_k<<<NB / 256, 256, 0, stream>>>(pdot, pesq, pmsq, pms, sims, mst);
  softmax_out_k<<<1, 1024, 0, stream>>>(sims, mst, out);
}

// Round 15
// 105.170 us; speedup vs baseline: 1.0723x; 1.0085x over previous
//
#include <hip/hip_runtime.h>

#define NB 8192   // batch
#define NC 1024   // controller width (K)
#define NM 4096   // memory size (N)
#define NCH 16    // NM / 256 (256-col chunks per row)

typedef __attribute__((ext_vector_type(8))) short bf16x8;
typedef __attribute__((ext_vector_type(4))) float f32x4;

__device__ __forceinline__ unsigned short f2bf(float x) {
  unsigned int u = __float_as_uint(x);
  u += 0x7FFFu + ((u >> 16) & 1u);
  return (unsigned short)(u >> 16);
}
__device__ __forceinline__ float bf2f(unsigned short h) {
  return __uint_as_float(((unsigned int)h) << 16);
}
__device__ __forceinline__ unsigned int pk2(float a, float b) {
  return (unsigned int)f2bf(a) | ((unsigned int)f2bf(b) << 16);
}

__device__ __forceinline__ void gload_lds16(const void* g, void* l) {
  __builtin_amdgcn_global_load_lds(
      (const __attribute__((address_space(1))) unsigned int*)g,
      (__attribute__((address_space(3))) unsigned int*)l, 16, 0, 0);
}

#define DSR(dst, addr, IMM) \
  asm volatile("ds_read_b128 %0, %1 offset:" IMM : "=v"(dst) : "v"(addr))

// Raw barrier (no implicit waitcnt drain); "memory" orders compiler mem ops.
#define BAR asm volatile("s_barrier" ::: "memory")
#define SBAR __builtin_amdgcn_sched_barrier(0)

// ------- Kernel 0: fused prep: W [K,N] f32 -> Wt [N,K] bf16  AND co -> bf16 ----
__global__ __launch_bounds__(256) void prep_k(const float* __restrict__ W,
                                              unsigned short* __restrict__ Wt,
                                              const float* __restrict__ coin,
                                              unsigned short* __restrict__ Abf) {
  __shared__ float tile[64][65];
  const int bid = blockIdx.x;
  const int t = threadIdx.x;
  if (bid < 1024) {  // ---- convW part ----
    const int n0 = (bid & 63) * 64, k0 = (bid >> 6) * 64;
    const int r = t >> 2, q = t & 3;
    const float4* src = reinterpret_cast<const float4*>(W + (size_t)(k0 + r) * NM + n0 + q * 16);
    float4 x0 = src[0], x1 = src[1], x2 = src[2], x3 = src[3];
    float* tr = &tile[r][q * 16];
    tr[0]=x0.x; tr[1]=x0.y; tr[2]=x0.z;  tr[3]=x0.w;
    tr[4]=x1.x; tr[5]=x1.y; tr[6]=x1.z;  tr[7]=x1.w;
    tr[8]=x2.x; tr[9]=x2.y; tr[10]=x2.z; tr[11]=x2.w;
    tr[12]=x3.x; tr[13]=x3.y; tr[14]=x3.z; tr[15]=x3.w;
    __syncthreads();
    unsigned int pk[8];
#pragma unroll
    for (int i = 0; i < 8; ++i)
      pk[i] = pk2(tile[q * 16 + 2 * i][r], tile[q * 16 + 2 * i + 1][r]);
    int4* dst = reinterpret_cast<int4*>(Wt + (size_t)(n0 + r) * NC + k0 + q * 16);
    dst[0] = make_int4((int)pk[0], (int)pk[1], (int)pk[2], (int)pk[3]);
    dst[1] = make_int4((int)pk[4], (int)pk[5], (int)pk[6], (int)pk[7]);
  } else {  // ---- convA part ----
    const size_t i = ((size_t)(bid - 1024) * 256 + t) * 8;
    const float4* s = reinterpret_cast<const float4*>(coin + i);
    float4 x0 = s[0], x1 = s[1];
    int4 o = make_int4((int)pk2(x0.x, x0.y), (int)pk2(x0.z, x0.w),
                       (int)pk2(x1.x, x1.y), (int)pk2(x1.z, x1.w));
    *reinterpret_cast<int4*>(Abf + i) = o;
  }
}

// ------- Kernel 2: 256x256-tile 8-phase bf16 MFMA GEMM, INTERLEAVED
//         MFMA<->ds_read phases (reads for p+1 issued between MFMA groups of p;
//         lgkmcnt(0) deferred to p+1 top -> zero read-latency exposure)
//         + two-phase fused epilogue -------
__global__ __launch_bounds__(512) void gemm_fused(
    const unsigned short* __restrict__ Abf, const float* __restrict__ memry,
    const unsigned short* __restrict__ Wt, const float* __restrict__ bvec,
    float* __restrict__ pdotg, float* __restrict__ pesqg,
    float* __restrict__ pmsqg, float* __restrict__ pmsg) {
  __shared__ __align__(16) unsigned short LDS[2][4][8192];  // 128 KiB
  const int bm = blockIdx.x, bn = blockIdx.y;
  const int row0 = bm * 256, col0 = bn * 256;
  const int t = threadIdx.x;
  const int wid = t >> 6, lane = t & 63;
  const int wr = wid >> 2, wc = wid & 3;          // 2 x 4 waves
  const int l15 = lane & 15, lg = lane >> 4;
  const int ga8 = (lg ^ ((l15 >> 1) & 3)) * 8;    // swizzled k-granule (halfwords)

  f32x4 acc[8][4];
#pragma unroll
  for (int mi = 0; mi < 8; ++mi)
#pragma unroll
    for (int ni = 0; ni < 4; ++ni) acc[mi][ni] = (f32x4){0.f, 0.f, 0.f, 0.f};

  const unsigned ldsbase =
      (unsigned)(uintptr_t)(__attribute__((address_space(3))) void*)&LDS[0][0][0];
  const unsigned abase = ldsbase + ((wr * 128 + l15) * 32 + ga8) * 2;
  const unsigned bbase = ldsbase + 32768 + ((wc * 64 + l15) * 32 + ga8) * 2;

  const int srow0 = t >> 2;
  const int sk8 = ((t & 3) ^ ((srow0 >> 1) & 3)) * 8;
  const unsigned short* gA = Abf + (size_t)(row0 + srow0) * NC + sk8;
  const unsigned short* gB = Wt + (size_t)(col0 + srow0) * NC + sk8;

#define STG(SL, TY, KT)                                                      \
  {                                                                          \
    const unsigned short* s0 = ((TY) <= 1 ? gA : gB) + (KT) * 64 + ((TY)&1) * 32; \
    gload_lds16(s0, &LDS[SL][TY][t * 8]);                                    \
    gload_lds16(s0 + (size_t)128 * NC, &LDS[SL][TY][t * 8 + 4096]);          \
  }
#define NOSTG
#define VM10 asm volatile("s_waitcnt vmcnt(10)" ::: "memory")
#define VM8 asm volatile("s_waitcnt vmcnt(8)" ::: "memory")
#define VM4 asm volatile("s_waitcnt vmcnt(4)" ::: "memory")
#define VM0 asm volatile("s_waitcnt vmcnt(0)" ::: "memory")
#define NOVM

#define MFMG(ACCH, MI, AMF, BMF)                                             \
  _Pragma("unroll") for (int ni = 0; ni < 4; ++ni)                           \
      acc[(ACCH)*4 + (MI)][ni] = __builtin_amdgcn_mfma_f32_16x16x32_bf16(    \
          AMF[MI], BMF[ni], acc[(ACCH)*4 + (MI)][ni], 0, 0, 0);

  // phase p: lgkm(0) [p-1 reads done, had full cluster to retire] ->
  //   MFMA g0 -> B-reads(p+1) -> g1 -> A-reads(p+1) -> g2 -> STG+VM -> g3 -> BAR
#define PH(ACCH, AMF, BMF, LDB, BLD, LDA, ALD, NSL, NS, NMH, STAGE, VM)      \
  {                                                                          \
    asm volatile("s_waitcnt lgkmcnt(0)" ::: "memory");                       \
    SBAR;                                                                    \
    __builtin_amdgcn_s_setprio(1);                                           \
    MFMG(ACCH, 0, AMF, BMF);                                                 \
    SBAR;                                                                    \
    if (LDB) {                                                               \
      const unsigned ba = bbase + (NSL)*65536 + (NS)*16384;                  \
      DSR(BLD[0], ba, "0");    DSR(BLD[1], ba, "1024");                      \
      DSR(BLD[2], ba, "2048"); DSR(BLD[3], ba, "3072");                      \
    }                                                                        \
    SBAR;                                                                    \
    MFMG(ACCH, 1, AMF, BMF);                                                 \
    SBAR;                                                                    \
    if (LDA) {                                                               \
      const unsigned aa = abase + (NSL)*65536 + (NS)*16384 + (NMH)*4096;     \
      DSR(ALD[0], aa, "0");    DSR(ALD[1], aa, "1024");                      \
      DSR(ALD[2], aa, "2048"); DSR(ALD[3], aa, "3072");                      \
    }                                                                        \
    SBAR;                                                                    \
    MFMG(ACCH, 2, AMF, BMF);                                                 \
    SBAR;                                                                    \
    STAGE;                                                                   \
    VM;                                                                      \
    SBAR;                                                                    \
    MFMG(ACCH, 3, AMF, BMF);                                                 \
    __builtin_amdgcn_s_setprio(0);                                           \
    BAR;                                                                     \
    SBAR;                                                                    \
  }

  // ---- prologue: slot0 (K-tile 0) + slot1 minus Ak1 (K-tile 1) ----
  STG(0, 2, 0); STG(0, 0, 0); STG(0, 3, 0); STG(0, 1, 0);
  STG(1, 2, 1); STG(1, 0, 1); STG(1, 3, 1);
  VM10;  // retire first 2 STGs (slot0 B-k0, A-k0)
  BAR;
  SBAR;

  bf16x8 aA[4], aB[4], bA[4], bB[4];
  // fragments for t1: B from LDS[0][2], A from LDS[0][0] MH0
  {
    const unsigned ba = bbase;
    DSR(bA[0], ba, "0");    DSR(bA[1], ba, "1024");
    DSR(bA[2], ba, "2048"); DSR(bA[3], ba, "3072");
    const unsigned aa = abase;
    DSR(aA[0], aa, "0");    DSR(aA[1], aa, "1024");
    DSR(aA[2], aa, "2048"); DSR(aA[3], aa, "3072");
  }

  // ---- main loop: 7 iterations x 2 K-tiles ----
  for (int it = 0; it < 7; ++it) {
    const int c1 = 2 * it + 1, c2 = 2 * it + 2, c3 = 2 * it + 3;
    PH(0, aA, bA, 0, bB, 1, aB, 0, 0, 1, STG(1, 1, c1), VM8);   // t1
    PH(1, aB, bA, 1, bB, 1, aA, 0, 1, 0, STG(0, 2, c2), NOVM);  // t2
    PH(0, aA, bB, 0, bA, 1, aB, 0, 1, 1, STG(0, 0, c2), VM8);   // t3
    PH(1, aB, bB, 1, bA, 1, aA, 1, 0, 0, STG(0, 3, c2), NOVM);  // t4
    PH(0, aA, bA, 0, bB, 1, aB, 1, 0, 1, STG(0, 1, c2), VM8);   // t5
    PH(1, aB, bA, 1, bB, 1, aA, 1, 1, 0, STG(1, 2, c3), NOVM);  // t6
    PH(0, aA, bB, 0, bA, 1, aB, 1, 1, 1, STG(1, 0, c3), VM8);   // t7
    PH(1, aB, bB, 1, bA, 1, aA, 0, 0, 0, STG(1, 3, c3), NOVM);  // t8
  }
  // ---- final iteration (K-tiles 14, 15): drain vmcnt VM8 -> VM4 -> VM0 ----
  PH(0, aA, bA, 0, bB, 1, aB, 0, 0, 1, STG(1, 1, 15), VM8);   // f1
  PH(1, aB, bA, 1, bB, 1, aA, 0, 1, 0, NOSTG,         NOVM);  // f2
  PH(0, aA, bB, 0, bA, 1, aB, 0, 1, 1, NOSTG,         VM4);   // f3
  PH(1, aB, bB, 1, bA, 1, aA, 1, 0, 0, NOSTG,         NOVM);  // f4
  PH(0, aA, bA, 0, bB, 1, aB, 1, 0, 1, NOSTG,         VM0);   // f5
  PH(1, aB, bA, 1, bB, 1, aA, 1, 1, 0, NOSTG,         NOVM);  // f6
  PH(0, aA, bB, 0, bA, 1, aB, 1, 1, 1, NOSTG,         NOVM);  // f7
  PH(1, aB, bB, 0, bA, 0, aA, 0, 0, 0, NOSTG,         NOVM);  // f8
#undef PH
#undef MFMG
#undef STG

  // ---- E1: e = exp(z + b) -> bf16 into LDS [256][256], col-XOR banks ----
  asm volatile("s_waitcnt lgkmcnt(0)" ::: "memory");  // f7 reads (f8 used them) done
  unsigned short (*e_lds)[256] = reinterpret_cast<unsigned short(*)[256]>(&LDS[0][0][0]);
  float bv[4];
#pragma unroll
  for (int ni = 0; ni < 4; ++ni) bv[ni] = bvec[col0 + wc * 64 + ni * 16 + l15];
#pragma unroll
  for (int mi = 0; mi < 8; ++mi)
#pragma unroll
    for (int ni = 0; ni < 4; ++ni)
#pragma unroll
      for (int j = 0; j < 4; ++j) {
        const int rl = wr * 128 + mi * 16 + 4 * lg + j;
        const int cl = wc * 64 + ni * 16 + l15;
        e_lds[rl][cl ^ (((rl >> 2) & 3) << 4)] = f2bf(__expf(acc[mi][ni][j] + bv[ni]));
      }
  __syncthreads();

  // ---- E2: coalesced fused pass: per row, partials of e*m, e^2, m^2, m ----
  {
    const int halfl = lane >> 5, l31 = lane & 31;
    const int rbase = wid * 32;  // each wave owns 32 consecutive rows
#pragma unroll 8
    for (int i = 0; i < 16; ++i) {
      const int rl = rbase + 2 * i + halfl;
      const float4* mp = reinterpret_cast<const float4*>(
          memry + (size_t)(row0 + rl) * NM + col0 + l31 * 8);
      float4 m0 = mp[0], m1 = mp[1];
      bf16x8 ev = *reinterpret_cast<const bf16x8*>(
          &e_lds[rl][(l31 * 8) ^ (((rl >> 2) & 3) << 4)]);
      float mv[8] = {m0.x, m0.y, m0.z, m0.w, m1.x, m1.y, m1.z, m1.w};
      float pd = 0.f, pe = 0.f, pq = 0.f, pm = 0.f;
#pragma unroll
      for (int k = 0; k < 8; ++k) {
        float e = bf2f((unsigned short)ev[k]);
        pd += e * mv[k]; pe += e * e; pq += mv[k] * mv[k]; pm += mv[k];
      }
#pragma unroll
      for (int sh = 1; sh < 32; sh <<= 1) {
        pd += __shfl_xor(pd, sh); pe += __shfl_xor(pe, sh);
        pq += __shfl_xor(pq, sh); pm += __shfl_xor(pm, sh);
      }
      if (l31 == 0) {
        const int idx = (row0 + rl) * NCH + bn;
        pdotg[idx] = pd; pesqg[idx] = pe; pmsqg[idx] = pq; pmsg[idx] = pm;
      }
    }
  }
}

// ---------------- Kernel 3: reduce partials -> sims, msum ----------------
__global__ __launch_bounds__(256) void finalize_k(
    const float* __restrict__ pd, const float* __restrict__ pe,
    const float* __restrict__ pq, const float* __restrict__ pm,
    float* __restrict__ sims, float* __restrict__ mst) {
  const int r = blockIdx.x * 256 + threadIdx.x;
  float d = 0.f, e = 0.f, q = 0.f, m = 0.f;
#pragma unroll
  for (int i = 0; i < NCH; ++i) {
    d += pd[r * NCH + i];
    e += pe[r * NCH + i];
    q += pq[r * NCH + i];
    m += pm[r * NCH + i];
  }
  sims[r] = -d / (sqrtf(fmaxf(e, 1e-12f)) * sqrtf(fmaxf(q, 1e-12f)));
  mst[r] = m;
}

// ------------- Kernel 4: softmax over B=8192 + final scaling -------------
__global__ __launch_bounds__(1024) void softmax_out_k(
    const float* __restrict__ sims, const float* __restrict__ mst,
    float* __restrict__ out) {
  __shared__ float red[16];
  const int t = threadIdx.x;
  float v[8];
  float mx = -1e30f;
#pragma unroll
  for (int i = 0; i < 8; ++i) {
    v[i] = sims[t + i * 1024];
    mx = fmaxf(mx, v[i]);
  }
#pragma unroll
  for (int s = 1; s < 64; s <<= 1) mx = fmaxf(mx, __shfl_xor(mx, s));
  if ((t & 63) == 0) red[t >> 6] = mx;
  __syncthreads();
  float m2 = red[0];
#pragma unroll
  for (int i = 1; i < 16; ++i) m2 = fmaxf(m2, red[i]);
  mx = m2;
  float sum = 0.f;
#pragma unroll
  for (int i = 0; i < 8; ++i) sum += __expf(v[i] - mx);
#pragma unroll
  for (int s = 1; s < 64; s <<= 1) sum += __shfl_xor(sum, s);
  __syncthreads();
  if ((t & 63) == 0) red[t >> 6] = sum;
  __syncthreads();
  float s2 = 0.f;
#pragma unroll
  for (int i = 0; i < 16; ++i) s2 += red[i];
  const float inv = 1.0f / s2;
#pragma unroll
  for (int i = 0; i < 8; ++i)
    out[t + i * 1024] = __expf(v[i] - mx) * inv * mst[t + i * 1024];
}

extern "C" void kernel_launch(void* const* d_in, const int* in_sizes, int n_in,
                              void* d_out, int out_size, void* d_ws, size_t ws_size,
                              hipStream_t stream) {
  const float* memry = (const float*)d_in[0];  // [B, M]
  const float* co    = (const float*)d_in[1];  // [B, C]
  const float* W     = (const float*)d_in[2];  // [C, M]
  const float* bvec  = (const float*)d_in[3];  // [M]
  float* out = (float*)d_out;                  // [B]

  char* w = (char*)d_ws;
  unsigned short* Wt  = (unsigned short*)w;                       // 8 MiB
  unsigned short* Abf = Wt + (size_t)NM * NC;                     // 16 MiB
  float* pdot = (float*)(Abf + (size_t)NB * NC);                  // 8192*16 f32 each
  float* pesq = pdot + (size_t)NB * NCH;
  float* pmsq = pesq + (size_t)NB * NCH;
  float* pms  = pmsq + (size_t)NB * NCH;
  float* sims = pms  + (size_t)NB * NCH;
  float* mst  = sims + NB;

  prep_k<<<1024 + (size_t)NB * NC / (256 * 8), 256, 0, stream>>>(W, Wt, co, Abf);
  gemm_fused<<<dim3(NB / 256, NM / 256), 512, 0, stream>>>(Abf, memry, Wt, bvec,
                                                           pdot, pesq, pmsq, pms);
  finalize_k<<<NB / 256, 256, 0, stream>>>(pdot, pesq, pmsq, pms, sims, mst);
  softmax_out_k<<<1, 1024, 0, stream>>>(sims, mst, out);
}

// Round 16
// 103.727 us; speedup vs baseline: 1.0873x; 1.0139x over previous
//
#include <hip/hip_runtime.h>

#define NB 8192   // batch
#define NC 1024   // controller width (K)
#define NM 4096   // memory size (N)
#define NCH 16    // NM / 256 (256-col chunks per row)

typedef __attribute__((ext_vector_type(8))) short bf16x8;
typedef __attribute__((ext_vector_type(4))) float f32x4;

__device__ __forceinline__ unsigned short f2bf(float x) {
  unsigned int u = __float_as_uint(x);
  u += 0x7FFFu + ((u >> 16) & 1u);
  return (unsigned short)(u >> 16);
}
__device__ __forceinline__ float bf2f(unsigned short h) {
  return __uint_as_float(((unsigned int)h) << 16);
}
__device__ __forceinline__ unsigned int pk2(float a, float b) {
  return (unsigned int)f2bf(a) | ((unsigned int)f2bf(b) << 16);
}

__device__ __forceinline__ void gload_lds16(const void* g, void* l) {
  __builtin_amdgcn_global_load_lds(
      (const __attribute__((address_space(1))) unsigned int*)g,
      (__attribute__((address_space(3))) unsigned int*)l, 16, 0, 0);
}

#define DSR(dst, addr, IMM) \
  asm volatile("ds_read_b128 %0, %1 offset:" IMM : "=v"(dst) : "v"(addr))

// Raw barrier (no implicit waitcnt drain); "memory" orders compiler mem ops.
#define BAR asm volatile("s_barrier" ::: "memory")
#define SBAR __builtin_amdgcn_sched_barrier(0)
#define LGKM0 asm volatile("s_waitcnt lgkmcnt(0)" ::: "memory")

// ------- Kernel 0: fused prep: W [K,N] f32 -> Wt [N,K] bf16  AND co -> bf16 ----
__global__ __launch_bounds__(256) void prep_k(const float* __restrict__ W,
                                              unsigned short* __restrict__ Wt,
                                              const float* __restrict__ coin,
                                              unsigned short* __restrict__ Abf) {
  __shared__ float tile[64][65];
  const int bid = blockIdx.x;
  const int t = threadIdx.x;
  if (bid < 1024) {  // ---- convW part ----
    const int n0 = (bid & 63) * 64, k0 = (bid >> 6) * 64;
    const int r = t >> 2, q = t & 3;
    const float4* src = reinterpret_cast<const float4*>(W + (size_t)(k0 + r) * NM + n0 + q * 16);
    float4 x0 = src[0], x1 = src[1], x2 = src[2], x3 = src[3];
    float* tr = &tile[r][q * 16];
    tr[0]=x0.x; tr[1]=x0.y; tr[2]=x0.z;  tr[3]=x0.w;
    tr[4]=x1.x; tr[5]=x1.y; tr[6]=x1.z;  tr[7]=x1.w;
    tr[8]=x2.x; tr[9]=x2.y; tr[10]=x2.z; tr[11]=x2.w;
    tr[12]=x3.x; tr[13]=x3.y; tr[14]=x3.z; tr[15]=x3.w;
    __syncthreads();
    unsigned int pk[8];
#pragma unroll
    for (int i = 0; i < 8; ++i)
      pk[i] = pk2(tile[q * 16 + 2 * i][r], tile[q * 16 + 2 * i + 1][r]);
    int4* dst = reinterpret_cast<int4*>(Wt + (size_t)(n0 + r) * NC + k0 + q * 16);
    dst[0] = make_int4((int)pk[0], (int)pk[1], (int)pk[2], (int)pk[3]);
    dst[1] = make_int4((int)pk[4], (int)pk[5], (int)pk[6], (int)pk[7]);
  } else {  // ---- convA part ----
    const size_t i = ((size_t)(bid - 1024) * 256 + t) * 8;
    const float4* s = reinterpret_cast<const float4*>(coin + i);
    float4 x0 = s[0], x1 = s[1];
    int4 o = make_int4((int)pk2(x0.x, x0.y), (int)pk2(x0.z, x0.w),
                       (int)pk2(x1.x, x1.y), (int)pk2(x1.z, x1.w));
    *reinterpret_cast<int4*>(Abf + i) = o;
  }
}

// ------- Kernel 2: 256x256-tile bf16 MFMA GEMM, MERGED 32-MFMA phases
//         (32 phases total; per-phase overhead amortized 2x), A-MH1 register
//         reuse, counted vmcnt(4)/phase + two-phase fused epilogue -------
// Phase P computes (slot (P>>1)&1, khalf P&1) for BOTH row-halves MH0/MH1.
// Frag sets X/Y alternate by P parity: B + A-MH0 double-buffered (read during
// P-1); A-MH1 read mid-phase into the just-consumed U.A registers.
__global__ __launch_bounds__(512) void gemm_fused(
    const unsigned short* __restrict__ Abf, const float* __restrict__ memry,
    const unsigned short* __restrict__ Wt, const float* __restrict__ bvec,
    float* __restrict__ pdotg, float* __restrict__ pesqg,
    float* __restrict__ pmsqg, float* __restrict__ pmsg) {
  __shared__ __align__(16) unsigned short LDS[2][4][8192];  // 128 KiB
  const int bm = blockIdx.x, bn = blockIdx.y;
  const int row0 = bm * 256, col0 = bn * 256;
  const int t = threadIdx.x;
  const int wid = t >> 6, lane = t & 63;
  const int wr = wid >> 2, wc = wid & 3;          // 2 x 4 waves
  const int l15 = lane & 15, lg = lane >> 4;
  const int ga8 = (lg ^ ((l15 >> 1) & 3)) * 8;    // swizzled k-granule (halfwords)

  f32x4 acc[8][4];
#pragma unroll
  for (int mi = 0; mi < 8; ++mi)
#pragma unroll
    for (int ni = 0; ni < 4; ++ni) acc[mi][ni] = (f32x4){0.f, 0.f, 0.f, 0.f};

  const unsigned ldsbase =
      (unsigned)(uintptr_t)(__attribute__((address_space(3))) void*)&LDS[0][0][0];
  const unsigned abase = ldsbase + ((wr * 128 + l15) * 32 + ga8) * 2;
  const unsigned bbase = ldsbase + 32768 + ((wc * 64 + l15) * 32 + ga8) * 2;

  const int srow0 = t >> 2;
  const int sk8 = ((t & 3) ^ ((srow0 >> 1) & 3)) * 8;
  const unsigned short* gA = Abf + (size_t)(row0 + srow0) * NC + sk8;
  const unsigned short* gB = Wt + (size_t)(col0 + srow0) * NC + sk8;

#define STG(SL, TY, KT)                                                      \
  {                                                                          \
    const unsigned short* s0 = ((TY) <= 1 ? gA : gB) + (KT) * 64 + ((TY)&1) * 32; \
    gload_lds16(s0, &LDS[SL][TY][t * 8]);                                    \
    gload_lds16(s0 + (size_t)128 * NC, &LDS[SL][TY][t * 8 + 4096]);          \
  }
#define NOSTG
#define VM8 asm volatile("s_waitcnt vmcnt(8)" ::: "memory")
#define VM4 asm volatile("s_waitcnt vmcnt(4)" ::: "memory")
#define VM0 asm volatile("s_waitcnt vmcnt(0)" ::: "memory")
#define NOVM

#define MFMG0(UA, UB, MI)                                                    \
  _Pragma("unroll") for (int ni = 0; ni < 4; ++ni)                           \
      acc[MI][ni] = __builtin_amdgcn_mfma_f32_16x16x32_bf16(                 \
          UA[MI], UB[ni], acc[MI][ni], 0, 0, 0);
#define MFMG1(UA, UB, MI)                                                    \
  _Pragma("unroll") for (int ni = 0; ni < 4; ++ni)                           \
      acc[4 + (MI)][ni] = __builtin_amdgcn_mfma_f32_16x16x32_bf16(           \
          UA[MI], UB[ni], acc[4 + (MI)][ni], 0, 0, 0);

  // phase: lgkm0 -> 4x{MFMA-MH0 | V-reads/STG1} -> UA<-MH1 reads -> lgkm0 ->
  //        4x{MFMA-MH1 | STG2/VM} -> BAR
#define PH(UA, UB, VA, VB, DOREAD, NSL, NS, CSL, CS, STG1, STG2, VM)         \
  {                                                                          \
    LGKM0;                                                                   \
    SBAR;                                                                    \
    __builtin_amdgcn_s_setprio(1);                                           \
    MFMG0(UA, UB, 0);                                                        \
    SBAR;                                                                    \
    if (DOREAD) {                                                            \
      const unsigned ba = bbase + (NSL)*65536 + (NS)*16384;                  \
      DSR(VB[0], ba, "0");    DSR(VB[1], ba, "1024");                        \
      DSR(VB[2], ba, "2048"); DSR(VB[3], ba, "3072");                        \
    }                                                                        \
    SBAR;                                                                    \
    MFMG0(UA, UB, 1);                                                        \
    SBAR;                                                                    \
    if (DOREAD) {                                                            \
      const unsigned aa = abase + (NSL)*65536 + (NS)*16384;                  \
      DSR(VA[0], aa, "0");    DSR(VA[1], aa, "1024");                        \
      DSR(VA[2], aa, "2048"); DSR(VA[3], aa, "3072");                        \
    }                                                                        \
    SBAR;                                                                    \
    MFMG0(UA, UB, 2);                                                        \
    SBAR;                                                                    \
    STG1;                                                                    \
    SBAR;                                                                    \
    MFMG0(UA, UB, 3);                                                        \
    SBAR;                                                                    \
    {                                                                        \
      const unsigned ca = abase + (CSL)*65536 + (CS)*16384 + 4096;           \
      DSR(UA[0], ca, "0");    DSR(UA[1], ca, "1024");                        \
      DSR(UA[2], ca, "2048"); DSR(UA[3], ca, "3072");                        \
    }                                                                        \
    SBAR;                                                                    \
    LGKM0;                                                                   \
    SBAR;                                                                    \
    MFMG1(UA, UB, 0);                                                        \
    SBAR;                                                                    \
    STG2;                                                                    \
    SBAR;                                                                    \
    MFMG1(UA, UB, 1);                                                        \
    SBAR;                                                                    \
    VM;                                                                      \
    SBAR;                                                                    \
    MFMG1(UA, UB, 2);                                                        \
    MFMG1(UA, UB, 3);                                                        \
    __builtin_amdgcn_s_setprio(0);                                           \
    BAR;                                                                     \
    SBAR;                                                                    \
  }

  // ---- prologue: K-tile 0 -> slot0 (8 vmem), K-tile 1 -> slot1 (8 vmem) ----
  STG(0, 0, 0); STG(0, 2, 0); STG(0, 1, 0); STG(0, 3, 0);
  STG(1, 0, 1); STG(1, 2, 1); STG(1, 1, 1); STG(1, 3, 1);
  VM8;  // slot0 fully landed
  BAR;
  SBAR;

  bf16x8 xA[4], xB[4], yA[4], yB[4];
  // prologue fragment reads for phase 0: B + A-MH0 of (slot0, k0)
  {
    DSR(xB[0], bbase, "0");    DSR(xB[1], bbase, "1024");
    DSR(xB[2], bbase, "2048"); DSR(xB[3], bbase, "3072");
    DSR(xA[0], abase, "0");    DSR(xA[1], abase, "1024");
    DSR(xA[2], abase, "2048"); DSR(xA[3], abase, "3072");
  }

  // ---- P0: compute (0,0); read V=(0,1); MH1 from (0,0) ----
  PH(xA, xB, yA, yB, 1, 0, 1, 0, 0, NOSTG, NOSTG, VM4);
  // ---- main loop: P = 4it+1 .. 4it+4 ----
  for (int it = 0; it < 7; ++it) {
    const int c2 = 2 * it + 2, c3 = 2 * it + 3;
    PH(yA, yB, xA, xB, 1, 1, 0, 0, 1, STG(0, 0, c2), STG(0, 2, c2), VM4);  // (0,1)
    PH(xA, xB, yA, yB, 1, 1, 1, 1, 0, STG(0, 1, c2), STG(0, 3, c2), VM4);  // (1,0)
    PH(yA, yB, xA, xB, 1, 0, 0, 1, 1, STG(1, 0, c3), STG(1, 2, c3), VM4);  // (1,1)
    PH(xA, xB, yA, yB, 1, 0, 1, 0, 0, STG(1, 1, c3), STG(1, 3, c3), VM4);  // (0,0) next pair
  }
  // ---- drain: P29 (0,1) K14, P30 (1,0) K15, P31 (1,1) K15 ----
  PH(yA, yB, xA, xB, 1, 1, 0, 0, 1, NOSTG, NOSTG, VM0);
  PH(xA, xB, yA, yB, 1, 1, 1, 1, 0, NOSTG, NOSTG, NOVM);
  PH(yA, yB, xA, xB, 0, 0, 0, 1, 1, NOSTG, NOSTG, NOVM);
#undef PH
#undef MFMG0
#undef MFMG1
#undef STG

  // ---- E1: e = exp(z + b) -> bf16 into LDS [256][256], col-XOR banks ----
  LGKM0;
  unsigned short (*e_lds)[256] = reinterpret_cast<unsigned short(*)[256]>(&LDS[0][0][0]);
  float bv[4];
#pragma unroll
  for (int ni = 0; ni < 4; ++ni) bv[ni] = bvec[col0 + wc * 64 + ni * 16 + l15];
#pragma unroll
  for (int mi = 0; mi < 8; ++mi)
#pragma unroll
    for (int ni = 0; ni < 4; ++ni)
#pragma unroll
      for (int j = 0; j < 4; ++j) {
        const int rl = wr * 128 + mi * 16 + 4 * lg + j;
        const int cl = wc * 64 + ni * 16 + l15;
        e_lds[rl][cl ^ (((rl >> 2) & 3) << 4)] = f2bf(__expf(acc[mi][ni][j] + bv[ni]));
      }
  __syncthreads();

  // ---- E2: coalesced fused pass: per row, partials of e*m, e^2, m^2, m ----
  {
    const int halfl = lane >> 5, l31 = lane & 31;
    const int rbase = wid * 32;  // each wave owns 32 consecutive rows
#pragma unroll 8
    for (int i = 0; i < 16; ++i) {
      const int rl = rbase + 2 * i + halfl;
      const float4* mp = reinterpret_cast<const float4*>(
          memry + (size_t)(row0 + rl) * NM + col0 + l31 * 8);
      float4 m0 = mp[0], m1 = mp[1];
      bf16x8 ev = *reinterpret_cast<const bf16x8*>(
          &e_lds[rl][(l31 * 8) ^ (((rl >> 2) & 3) << 4)]);
      float mv[8] = {m0.x, m0.y, m0.z, m0.w, m1.x, m1.y, m1.z, m1.w};
      float pd = 0.f, pe = 0.f, pq = 0.f, pm = 0.f;
#pragma unroll
      for (int k = 0; k < 8; ++k) {
        float e = bf2f((unsigned short)ev[k]);
        pd += e * mv[k]; pe += e * e; pq += mv[k] * mv[k]; pm += mv[k];
      }
#pragma unroll
      for (int sh = 1; sh < 32; sh <<= 1) {
        pd += __shfl_xor(pd, sh); pe += __shfl_xor(pe, sh);
        pq += __shfl_xor(pq, sh); pm += __shfl_xor(pm, sh);
      }
      if (l31 == 0) {
        const int idx = (row0 + rl) * NCH + bn;
        pdotg[idx] = pd; pesqg[idx] = pe; pmsqg[idx] = pq; pmsg[idx] = pm;
      }
    }
  }
}

// ---------------- Kernel 3: reduce partials -> sims, msum ----------------
__global__ __launch_bounds__(256) void finalize_k(
    const float* __restrict__ pd, const float* __restrict__ pe,
    const float* __restrict__ pq, const float* __restrict__ pm,
    float* __restrict__ sims, float* __restrict__ mst) {
  const int r = blockIdx.x * 256 + threadIdx.x;
  float d = 0.f, e = 0.f, q = 0.f, m = 0.f;
#pragma unroll
  for (int i = 0; i < NCH; ++i) {
    d += pd[r * NCH + i];
    e += pe[r * NCH + i];
    q += pq[r * NCH + i];
    m += pm[r * NCH + i];
  }
  sims[r] = -d / (sqrtf(fmaxf(e, 1e-12f)) * sqrtf(fmaxf(q, 1e-12f)));
  mst[r] = m;
}

// ------------- Kernel 4: softmax over B=8192 + final scaling -------------
__global__ __launch_bounds__(1024) void softmax_out_k(
    const float* __restrict__ sims, const float* __restrict__ mst,
    float* __restrict__ out) {
  __shared__ float red[16];
  const int t = threadIdx.x;
  float v[8];
  float mx = -1e30f;
#pragma unroll
  for (int i = 0; i < 8; ++i) {
    v[i] = sims[t + i * 1024];
    mx = fmaxf(mx, v[i]);
  }
#pragma unroll
  for (int s = 1; s < 64; s <<= 1) mx = fmaxf(mx, __shfl_xor(mx, s));
  if ((t & 63) == 0) red[t >> 6] = mx;
  __syncthreads();
  float m2 = red[0];
#pragma unroll
  for (int i = 1; i < 16; ++i) m2 = fmaxf(m2, red[i]);
  mx = m2;
  float sum = 0.f;
#pragma unroll
  for (int i = 0; i < 8; ++i) sum += __expf(v[i] - mx);
#pragma unroll
  for (int s = 1; s < 64; s <<= 1) sum += __shfl_xor(sum, s);
  __syncthreads();
  if ((t & 63) == 0) red[t >> 6] = sum;
  __syncthreads();
  float s2 = 0.f;
#pragma unroll
  for (int i = 0; i < 16; ++i) s2 += red[i];
  const float inv = 1.0f / s2;
#pragma unroll
  for (int i = 0; i < 8; ++i)
    out[t + i * 1024] = __expf(v[i] - mx) * inv * mst[t + i * 1024];
}

extern "C" void kernel_launch(void* const* d_in, const int* in_sizes, int n_in,
                              void* d_out, int out_size, void* d_ws, size_t ws_size,
                              hipStream_t stream) {
  const float* memry = (const float*)d_in[0];  // [B, M]
  const float* co    = (const float*)d_in[1];  // [B, C]
  const float* W     = (const float*)d_in[2];  // [C, M]
  const float* bvec  = (const float*)d_in[3];  // [M]
  float* out = (float*)d_out;                  // [B]

  char* w = (char*)d_ws;
  unsigned short* Wt  = (unsigned short*)w;                       // 8 MiB
  unsigned short* Abf = Wt + (size_t)NM * NC;                     // 16 MiB
  float* pdot = (float*)(Abf + (size_t)NB * NC);                  // 8192*16 f32 each
  float* pesq = pdot + (size_t)NB * NCH;
  float* pmsq = pesq + (size_t)NB * NCH;
  float* pms  = pmsq + (size_t)NB * NCH;
  float* sims = pms  + (size_t)NB * NCH;
  float* mst  = sims + NB;

  prep_k<<<1024 + (size_t)NB * NC / (256 * 8), 256, 0, stream>>>(W, Wt, co, Abf);
  gemm_fused<<<dim3(NB / 256, NM / 256), 512, 0, stream>>>(Abf, memry, Wt, bvec,
                                                           pdot, pesq, pmsq, pms);
  finalize_k<<<NB / 256, 256, 0, stream>>>(pdot, pesq, pmsq, pms, sims, mst);
  softmax_out_k<<<1, 1024, 0, stream>>>(sims, mst, out);
}